// Round 16
// baseline (27.673 us; speedup 1.0000x reference)
//
#include <hip/hip_runtime.h>

#define BB 4
#define RR 160
#define HH 128
#define WW 128
#define CC 64
#define NREG 32
#define PH 7
#define PW 7
#define NTHR 448
#define IOU_THRF 0.4f
#define FLAG_MAGIC 0x5A17CAFEu

// floor division (Python // semantics) for possibly-negative numerators
__device__ __forceinline__ int fdiv(int a, int b) {
    int q = a / b, r = a % b;
    return (r != 0 && ((r < 0) != (b < 0))) ? q - 1 : q;
}

__device__ __forceinline__ void fix_span(int& lo, int& hi, int p, int s) {
    int pad = p - (hi - lo);
    bool fmin = lo < fdiv(pad, 2);
    bool fmax = (s - hi) < fdiv(1 + pad, 2);
    bool sym = (pad > 0) && !(fmin || fmax);
    int lo2 = sym ? lo - fdiv(pad, 2) : lo;
    int hi2 = sym ? hi + fdiv(1 + pad, 2) : hi;
    if ((pad > 0) && fmin) { lo2 = 0; hi2 = p; }
    if ((pad > 0) && fmax) { lo2 = s - p; hi2 = s; }
    lo = lo2; hi = hi2;
}

__device__ __forceinline__ float4 fmax4(float4 a, float4 b) {
    a.x = fmaxf(a.x, b.x); a.y = fmaxf(a.y, b.y);
    a.z = fmaxf(a.z, b.z); a.w = fmaxf(a.w, b.w);
    return a;
}

// R13-verified NMS phase (7-wave static map, register-hoisted ballot build).
__device__ __forceinline__ void nms_phase(const float* __restrict__ roi,
                                          int* __restrict__ boxes_out,
                                          int b, int tid, int wid, int lane,
                                          float* sx, float* sy, float* sx1,
                                          float* sy1, float* sarea,
                                          unsigned long long (*nsup)[3]) {
    const float* rb = roi + (size_t)b * RR * 4;
    if (tid < RR) {
        const float4 r4 = reinterpret_cast<const float4*>(rb)[tid];
        sx[tid] = r4.x; sy[tid] = r4.y;
        sx1[tid] = __fadd_rn(r4.x, r4.z);
        sy1[tid] = __fadd_rn(r4.y, r4.w);
        sarea[tid] = __fmul_rn(r4.z, r4.w);
    }
    __syncthreads();

    // wave0: w0 t[0,64); waves1-2: w1 t[0,64),[64,128); waves3-6: w2 quarters of [0,159)
    {
        int w, tlo, thi;
        if (wid == 0)      { w = 0; tlo = 0;              thi = 64; }
        else if (wid <= 2) { w = 1; tlo = (wid - 1) * 64; thi = wid * 64; }
        else               { w = 2; int c = wid - 3; tlo = c * 159 / 4; thi = (c + 1) * 159 / 4; }

        const int j  = w * 64 + lane;
        const int jc = j < RR ? j : RR - 1;
        const float jx0 = sx[jc], jy0 = sy[jc], jx1 = sx1[jc], jy1 = sy1[jc], ja = sarea[jc];
        const bool jok = j < RR;

        #pragma unroll 4
        for (int t = tlo; t < thi; ++t) {
            const float xa = fmaxf(sx[t], jx0);
            const float ya = fmaxf(sy[t], jy0);
            const float xb = fminf(sx1[t], jx1);
            const float yb = fminf(sy1[t], jy1);
            const float iw  = fmaxf(__fsub_rn(xb, xa), 0.0f);
            const float ihh = fmaxf(__fsub_rn(yb, ya), 0.0f);
            const float inter = __fmul_rn(iw, ihh);
            const float denom = __fsub_rn(__fadd_rn(sarea[t], ja), inter);
            const bool pred = jok && (j > t) && (__fdiv_rn(inter, denom) > IOU_THRF);
            const unsigned long long bal = __ballot(pred);
            if (lane == 0) nsup[t][w] = ~bal;
        }
    }
    __syncthreads();

    if (tid < NREG) {
        // sequential keep-scan (exact lax.scan semantics), OR-AND form
        unsigned long long k0 = ~0ull, k1 = ~0ull, k2 = (1ull << 32) - 1;
        #pragma unroll 8
        for (int t = 0; t < 64; ++t) {
            unsigned long long mb = ((k0 >> t) & 1ull) - 1ull;
            k0 &= nsup[t][0] | mb;
            k1 &= nsup[t][1] | mb;
            k2 &= nsup[t][2] | mb;
        }
        #pragma unroll 8
        for (int t = 64; t < 128; ++t) {
            unsigned long long mb = ((k1 >> (t - 64)) & 1ull) - 1ull;
            k1 &= nsup[t][1] | mb;
            k2 &= nsup[t][2] | mb;
        }
        #pragma unroll 8
        for (int t = 128; t < RR - 1; ++t) {
            unsigned long long mb = ((k2 >> (t - 128)) & 1ull) - 1ull;
            k2 &= nsup[t][2] | mb;
        }

        int src = RR - 1;
        int target = tid;
        unsigned long long words[3] = {k0, k1, k2};
        #pragma unroll
        for (int w = 0; w < 3; ++w) {
            int pc = __popcll(words[w]);
            if (target < pc) {
                unsigned long long xw = words[w];
                for (int p = 0; p < target; ++p) xw &= xw - 1;
                src = w * 64 + (__ffsll((long long)xw) - 1);
                break;
            }
            target -= pc;
        }

        int x0 = max(0, (int)sx[src]);
        int y0 = max(0, (int)sy[src]);
        int x1 = min(WW, (int)sx1[src]);
        int y1 = min(HH, (int)sy1[src]);
        fix_span(x0, x1, PW, WW);
        fix_span(y0, y1, PH, HH);
        int* o = boxes_out + ((size_t)b * NREG + tid) * 4;
        o[0] = x0; o[1] = y0; o[2] = x1 - x0; o[3] = y1 - y0;
    }
}

// Single dispatch, 896 blocks x 448 thr (28 waves/CU -> whole grid co-resident).
// Blocks 0-3 run NMS once each (batch g), publish boxes + agent-RELEASE flag.
// Consumers poll ONLY their own batch's flag with RELAXED loads + s_sleep(16)
// (~30x less coherent-poll traffic than R13: no per-poll L1 invalidate, 1 flag
// not 4, 223 pollers/flag not 892), then ONE ACQUIRE load for ordering.
// Pool phase = R15's ILP-4 pool (4 indep accumulators per 4-row chunk) with
// safety clamps (no-ops for valid boxes; garbage can't fault or hang).
__global__ __launch_bounds__(NTHR)
void roipool_spin2(const float* __restrict__ feat, const float* __restrict__ roi,
                   float* __restrict__ out, int* __restrict__ boxes,
                   unsigned int* __restrict__ flags) {
    const int g = blockIdx.x;
    // pool decode: xcd x = g%8 owns (b,n) pairs [x*16, x*16+16)
    const int x = g & 7;
    const int q = g >> 3;
    const int pair = x * 16 + q / 7;
    const int i = q % 7;
    const int n = pair & (NREG - 1);
    const int b = pair >> 5;

    const int tid = threadIdx.x;
    const int wid = tid >> 6;
    const int lane = tid & 63;

    __shared__ float sx[RR], sy[RR], sx1[RR], sy1[RR], sarea[RR];
    __shared__ unsigned long long nsup[RR][3];

    // ---- produce: blocks 0-3 compute NMS for batch g ----
    if (g < BB) {
        nms_phase(roi, boxes, g, tid, wid, lane, sx, sy, sx1, sy1, sarea, nsup);
        __syncthreads();   // all box writes of this block done
        if (tid == 0)
            __hip_atomic_store(&flags[g], FLAG_MAGIC, __ATOMIC_RELEASE,
                               __HIP_MEMORY_SCOPE_AGENT);
    }

    // ---- wait: lane 0 polls OWN batch flag, relaxed; one acquire at the end ----
    if (tid == 0) {
        unsigned int v = __hip_atomic_load(&flags[b], __ATOMIC_RELAXED,
                                           __HIP_MEMORY_SCOPE_AGENT);
        for (int it = 0; v != FLAG_MAGIC && it < 200000; ++it) {
            __builtin_amdgcn_s_sleep(16);
            v = __hip_atomic_load(&flags[b], __ATOMIC_RELAXED,
                                  __HIP_MEMORY_SCOPE_AGENT);
        }
        (void)__hip_atomic_load(&flags[b], __ATOMIC_ACQUIRE,
                                __HIP_MEMORY_SCOPE_AGENT);
    }
    __syncthreads();

    // ---- pool (R15 ILP-4 form, clamped) ----
    const int wave = wid;                // jj, 0..6 (wave-uniform)
    const int poff = lane >> 4;          // 0..3 pixel offset within group
    const int cq   = lane & 15;          // 0..15 channel quad

    const int4 bx = *reinterpret_cast<const int4*>(boxes + ((size_t)b * NREG + n) * 4);
    const int bx0 = bx.x, by0 = bx.y, bw = bx.z, bh = bx.w;
    const int hs = bh / PH, wsz = bw / PW;

    int r0 = by0 + i * hs;
    int r1 = (i == PH - 1) ? (by0 + bh) : (r0 + hs);
    int c0 = bx0 + wave * wsz;
    int c1 = (wave == PW - 1) ? (bx0 + bw) : (c0 + wsz);
    // safety clamps (no-ops for valid boxes)
    r0 = min(max(r0, 0), HH - 1); r1 = min(max(r1, r0 + 1), HH);
    c0 = min(max(c0, 0), WW - 1); c1 = min(max(c1, c0 + 1), WW);
    const int nr = r1 - r0;
    const int ng = (c1 - c0 + 3) >> 2;

    const float* fb = feat + (size_t)b * HH * WW * CC + (size_t)cq * 4;

    const float4 NEG = make_float4(-INFINITY, -INFINITY, -INFINITY, -INFINITY);
    float4 a0 = NEG, a1 = NEG, a2 = NEG, a3 = NEG;

    for (int gg = 0; gg < ng; ++gg) {
        int px = c0 + (gg << 2) + poff;
        px = px < c1 ? px : c1 - 1;
        const float* colp = fb + (size_t)px * CC;
        for (int rr = 0; rr < nr; rr += 4) {
            const int q1 = min(rr + 1, nr - 1);
            const int q2 = min(rr + 2, nr - 1);
            const int q3 = min(rr + 3, nr - 1);
            const float4 t0 = *reinterpret_cast<const float4*>(colp + (size_t)(r0 + rr) * (WW * CC));
            const float4 t1 = *reinterpret_cast<const float4*>(colp + (size_t)(r0 + q1) * (WW * CC));
            const float4 t2 = *reinterpret_cast<const float4*>(colp + (size_t)(r0 + q2) * (WW * CC));
            const float4 t3 = *reinterpret_cast<const float4*>(colp + (size_t)(r0 + q3) * (WW * CC));
            a0 = fmax4(a0, t0);
            a1 = fmax4(a1, t1);
            a2 = fmax4(a2, t2);
            a3 = fmax4(a3, t3);
        }
    }
    float4 v = fmax4(fmax4(a0, a1), fmax4(a2, a3));

    // reduce over the 4 pixel-groups: lanes {cq, cq+16, cq+32, cq+48}
    v.x = fmaxf(v.x, __shfl_xor(v.x, 16));
    v.y = fmaxf(v.y, __shfl_xor(v.y, 16));
    v.z = fmaxf(v.z, __shfl_xor(v.z, 16));
    v.w = fmaxf(v.w, __shfl_xor(v.w, 16));
    v.x = fmaxf(v.x, __shfl_xor(v.x, 32));
    v.y = fmaxf(v.y, __shfl_xor(v.y, 32));
    v.z = fmaxf(v.z, __shfl_xor(v.z, 32));
    v.w = fmaxf(v.w, __shfl_xor(v.w, 32));

    if (poff == 0) {
        float4* o = reinterpret_cast<float4*>(
            out + ((((size_t)b * NREG + n) * PH + i) * PW + wave) * CC) + cq;
        *o = v;
    }
}

extern "C" void kernel_launch(void* const* d_in, const int* in_sizes, int n_in,
                              void* d_out, int out_size, void* d_ws, size_t ws_size,
                              hipStream_t stream) {
    const float* features = (const float*)d_in[0];
    const float* roi      = (const float*)d_in[1];
    float* out = (float*)d_out;
    int* boxes = (int*)d_ws;                          // 512 ints = 2 KB
    unsigned int* flags = (unsigned int*)d_ws + 512;  // 4 ints

    roipool_spin2<<<BB * NREG * PH, NTHR, 0, stream>>>(features, roi, out, boxes, flags);
}